// Round 1
// baseline (344.468 us; speedup 1.0000x reference)
//
#include <hip/hip_runtime.h>
#include <hip/hip_bf16.h>

using f32x4  = __attribute__((ext_vector_type(4))) float;
using bf16x8 = __attribute__((ext_vector_type(8))) short;

constexpr int BATCH = 8, SEQ = 1024, DIM = 768, NHEAD = 12, HDIM = 64;
constexpr int MROWS = BATCH * SEQ;   // 8192

__device__ __forceinline__ short f2bf(float f) {
    union { float f; unsigned u; } x; x.f = f;
    unsigned r = (x.u + 0x7fffu + ((x.u >> 16) & 1u)) >> 16;
    return (short)r;
}

// C[M,DIM] = A[M,K] @ W[DIM,K]^T + bias   (nn.Linear semantics, NT GEMM)
// tile 128x128, BK=32, 4 waves (2x2), each wave 64x64 via 4x4 16x16x32 MFMA
template <typename AT, bool OUT_BF16>
__global__ __launch_bounds__(256)
void gemm_bt(const AT* __restrict__ A, const float* __restrict__ W,
             const float* __restrict__ bias, void* __restrict__ Cout) {
    constexpr int K  = DIM;
    constexpr int NT = DIM / 128;  // 6 column tiles
    __shared__ short As[128][72];  // stride 144B: 16B-aligned rows, 2-way bank alias (free)
    __shared__ short Bs[128][72];

    const int bm = blockIdx.x / NT, bn = blockIdx.x % NT;
    const int m0 = bm * 128, n0 = bn * 128;
    const int t = threadIdx.x;
    const int lane = t & 63, w = t >> 6;
    const int wm = (w >> 1) * 64, wn = (w & 1) * 64;
    const int l16 = lane & 15, lg = lane >> 4;

    const int sr = t >> 1, sc = (t & 1) * 16;   // staging: 16 elems/thread

    f32x4 acc[4][4] = {};

    for (int k0 = 0; k0 < K; k0 += 32) {
        __syncthreads();
        // stage A tile (convert fp32->bf16 if needed)
        if constexpr (sizeof(AT) == 4) {
            const float* ap = (const float*)A + (long)(m0 + sr) * K + k0 + sc;
            float tmp[16];
            *(f32x4*)&tmp[0]  = *(const f32x4*)(ap + 0);
            *(f32x4*)&tmp[4]  = *(const f32x4*)(ap + 4);
            *(f32x4*)&tmp[8]  = *(const f32x4*)(ap + 8);
            *(f32x4*)&tmp[12] = *(const f32x4*)(ap + 12);
            short tb[16];
            #pragma unroll
            for (int j = 0; j < 16; ++j) tb[j] = f2bf(tmp[j]);
            *(bf16x8*)&As[sr][sc]     = *(bf16x8*)&tb[0];
            *(bf16x8*)&As[sr][sc + 8] = *(bf16x8*)&tb[8];
        } else {
            const short* ap = (const short*)A + (long)(m0 + sr) * K + k0 + sc;
            *(bf16x8*)&As[sr][sc]     = *(const bf16x8*)(ap);
            *(bf16x8*)&As[sr][sc + 8] = *(const bf16x8*)(ap + 8);
        }
        // stage W tile (always fp32 source)
        {
            const float* wp = W + (long)(n0 + sr) * K + k0 + sc;
            float tmp[16];
            *(f32x4*)&tmp[0]  = *(const f32x4*)(wp + 0);
            *(f32x4*)&tmp[4]  = *(const f32x4*)(wp + 4);
            *(f32x4*)&tmp[8]  = *(const f32x4*)(wp + 8);
            *(f32x4*)&tmp[12] = *(const f32x4*)(wp + 12);
            short tb[16];
            #pragma unroll
            for (int j = 0; j < 16; ++j) tb[j] = f2bf(tmp[j]);
            *(bf16x8*)&Bs[sr][sc]     = *(bf16x8*)&tb[0];
            *(bf16x8*)&Bs[sr][sc + 8] = *(bf16x8*)&tb[8];
        }
        __syncthreads();

        bf16x8 af[4], bfg[4];
        const int kc = lg * 8;
        #pragma unroll
        for (int mi = 0; mi < 4; ++mi)
            af[mi] = *(const bf16x8*)&As[wm + mi * 16 + l16][kc];
        #pragma unroll
        for (int ni = 0; ni < 4; ++ni)
            bfg[ni] = *(const bf16x8*)&Bs[wn + ni * 16 + l16][kc];
        #pragma unroll
        for (int mi = 0; mi < 4; ++mi)
            #pragma unroll
            for (int ni = 0; ni < 4; ++ni)
                acc[mi][ni] = __builtin_amdgcn_mfma_f32_16x16x32_bf16(
                    af[mi], bfg[ni], acc[mi][ni], 0, 0, 0);
    }

    // epilogue: C/D layout col=lane&15, row=(lane>>4)*4+j
    #pragma unroll
    for (int mi = 0; mi < 4; ++mi) {
        const int row = m0 + wm + mi * 16 + lg * 4;
        #pragma unroll
        for (int ni = 0; ni < 4; ++ni) {
            const int col = n0 + wn + ni * 16 + l16;
            const float bv = bias[col];
            #pragma unroll
            for (int j = 0; j < 4; ++j) {
                float val = acc[mi][ni][j] + bv;
                if constexpr (OUT_BF16)
                    ((short*)Cout)[(long)(row + j) * DIM + col] = f2bf(val);
                else
                    ((float*)Cout)[(long)(row + j) * DIM + col] = val;
            }
        }
    }
}

// Flash-style attention with bias + mask. One block = (b, h, 64 q-rows).
// 4 waves x 16 q-rows each. KV tiles of 64. Online softmax per q-row.
__global__ __launch_bounds__(256)
void attn_kernel(const short* __restrict__ Qp, const short* __restrict__ Kp,
                 const short* __restrict__ Vp, const float* __restrict__ bias,
                 const int* __restrict__ mask, short* __restrict__ Op) {
    __shared__ short Ks[64][72];      // K tile [key][hd]
    __shared__ short Vt[64][72];      // V tile transposed [hd][key]
    __shared__ short Ps[4][16][72];   // per-wave P [qrow][key]

    const int bid = blockIdx.x;
    const int qt = bid & 15;                 // SEQ/64 = 16 q-tiles
    const int h  = (bid >> 4) % NHEAD;
    const int b  = bid / (16 * NHEAD);
    const int t = threadIdx.x;
    const int lane = t & 63, w = t >> 6;
    const int l16 = lane & 15, lg = lane >> 4;

    // Q fragments: rows w*16 + l16, k = lg*8 (+0 / +32)
    const int qrow = qt * 64 + w * 16 + l16;
    const short* qptr = Qp + (long)(b * SEQ + qrow) * DIM + h * HDIM + lg * 8;
    const bf16x8 qf0 = *(const bf16x8*)qptr;
    const bf16x8 qf1 = *(const bf16x8*)(qptr + 32);

    f32x4 acc_o[4] = {};
    float m_run[4], l_run[4];
    #pragma unroll
    for (int j = 0; j < 4; ++j) { m_run[j] = -1e30f; l_run[j] = 0.f; }

    const int sr = t >> 2, sc = (t & 3) * 16;    // staging: 16 elems/thread
    constexpr float L2E = 1.4426950408889634f;

    for (int kt = 0; kt < SEQ / 64; ++kt) {
        __syncthreads();
        {   // stage K tile
            const short* kp = Kp + (long)(b * SEQ + kt * 64 + sr) * DIM + h * HDIM + sc;
            *(bf16x8*)&Ks[sr][sc]     = *(const bf16x8*)(kp);
            *(bf16x8*)&Ks[sr][sc + 8] = *(const bf16x8*)(kp + 8);
        }
        {   // stage V transposed
            const short* vp = Vp + (long)(b * SEQ + kt * 64 + sr) * DIM + h * HDIM + sc;
            short tmp[16];
            *(bf16x8*)&tmp[0] = *(const bf16x8*)(vp);
            *(bf16x8*)&tmp[8] = *(const bf16x8*)(vp + 8);
            #pragma unroll
            for (int j = 0; j < 16; ++j) Vt[sc + j][sr] = tmp[j];
        }
        __syncthreads();

        // S = Q K^T  (A=Q 16x64, B=K^T; K rows give B-frags directly)
        f32x4 s[4];
        #pragma unroll
        for (int c = 0; c < 4; ++c) {
            const bf16x8 kb0 = *(const bf16x8*)&Ks[c * 16 + l16][lg * 8];
            const bf16x8 kb1 = *(const bf16x8*)&Ks[c * 16 + l16][32 + lg * 8];
            f32x4 z = {};
            z    = __builtin_amdgcn_mfma_f32_16x16x32_bf16(qf0, kb0, z, 0, 0, 0);
            s[c] = __builtin_amdgcn_mfma_f32_16x16x32_bf16(qf1, kb1, z, 0, 0, 0);
        }

        // scale + bias + mask
        float p[4][4], mt[4];
        #pragma unroll
        for (int j = 0; j < 4; ++j) mt[j] = -1e30f;
        const int qg = qt * 64 + w * 16 + lg * 4;   // +j
        #pragma unroll
        for (int c = 0; c < 4; ++c) {
            const int kg = kt * 64 + c * 16 + l16;
            #pragma unroll
            for (int j = 0; j < 4; ++j) {
                float sv = s[c][j] * 0.125f
                    + bias[((long)(b * NHEAD + h) * SEQ + qg + j) * SEQ + kg];
                if (mask[((long)b * SEQ + qg + j) * SEQ + kg] == 0) sv = -1e30f;
                p[c][j] = sv;
                mt[j] = fmaxf(mt[j], sv);
            }
        }
        // row-max across the 16-lane group
        #pragma unroll
        for (int off = 1; off < 16; off <<= 1)
            #pragma unroll
            for (int j = 0; j < 4; ++j)
                mt[j] = fmaxf(mt[j], __shfl_xor(mt[j], off));

        float alpha[4], lt[4];
        #pragma unroll
        for (int j = 0; j < 4; ++j) {
            const float mn = fmaxf(m_run[j], mt[j]);
            alpha[j] = exp2f((m_run[j] - mn) * L2E);
            m_run[j] = mn;
            lt[j] = 0.f;
        }
        #pragma unroll
        for (int c = 0; c < 4; ++c)
            #pragma unroll
            for (int j = 0; j < 4; ++j) {
                const float e = exp2f((p[c][j] - m_run[j]) * L2E);
                p[c][j] = e;
                lt[j] += e;
            }
        #pragma unroll
        for (int off = 1; off < 16; off <<= 1)
            #pragma unroll
            for (int j = 0; j < 4; ++j)
                lt[j] += __shfl_xor(lt[j], off);
        #pragma unroll
        for (int j = 0; j < 4; ++j)
            l_run[j] = l_run[j] * alpha[j] + lt[j];

        // rescale O accumulators
        #pragma unroll
        for (int df = 0; df < 4; ++df)
            #pragma unroll
            for (int j = 0; j < 4; ++j)
                acc_o[df][j] *= alpha[j];

        // write P (C-layout) to per-wave LDS, re-read as A-fragments
        #pragma unroll
        for (int c = 0; c < 4; ++c)
            #pragma unroll
            for (int j = 0; j < 4; ++j)
                Ps[w][lg * 4 + j][c * 16 + l16] = f2bf(p[c][j]);
        __syncthreads();

        const bf16x8 pa0 = *(const bf16x8*)&Ps[w][l16][lg * 8];
        const bf16x8 pa1 = *(const bf16x8*)&Ps[w][l16][32 + lg * 8];
        #pragma unroll
        for (int df = 0; df < 4; ++df) {
            const bf16x8 vb0 = *(const bf16x8*)&Vt[df * 16 + l16][lg * 8];
            const bf16x8 vb1 = *(const bf16x8*)&Vt[df * 16 + l16][32 + lg * 8];
            acc_o[df] = __builtin_amdgcn_mfma_f32_16x16x32_bf16(pa0, vb0, acc_o[df], 0, 0, 0);
            acc_o[df] = __builtin_amdgcn_mfma_f32_16x16x32_bf16(pa1, vb1, acc_o[df], 0, 0, 0);
        }
    }

    // epilogue: O /= l, write bf16 to Op[b, q, h*64+d]
    #pragma unroll
    for (int df = 0; df < 4; ++df) {
        #pragma unroll
        for (int j = 0; j < 4; ++j) {
            const float val = acc_o[df][j] / fmaxf(l_run[j], 1e-20f);
            const int row = b * SEQ + qt * 64 + w * 16 + lg * 4 + j;
            const int col = h * HDIM + df * 16 + l16;
            Op[(long)row * DIM + col] = f2bf(val);
        }
    }
}

extern "C" void kernel_launch(void* const* d_in, const int* in_sizes, int n_in,
                              void* d_out, int out_size, void* d_ws, size_t ws_size,
                              hipStream_t stream) {
    const float* q         = (const float*)d_in[0];
    const float* k         = (const float*)d_in[1];
    const float* v         = (const float*)d_in[2];
    const float* attn_bias = (const float*)d_in[3];
    const int*   attn_mask = (const int*)d_in[4];
    const float* Wq = (const float*)d_in[5];
    const float* bq = (const float*)d_in[6];
    const float* Wk = (const float*)d_in[7];
    const float* bk = (const float*)d_in[8];
    const float* Wv = (const float*)d_in[9];
    const float* bv = (const float*)d_in[10];
    const float* Wo = (const float*)d_in[11];
    const float* bo = (const float*)d_in[12];
    float* out = (float*)d_out;

    short* Qp = (short*)d_ws;                    // [8192][768] bf16
    short* Kp = Qp + (long)MROWS * DIM;
    short* Vp = Kp + (long)MROWS * DIM;
    short* Op = Vp + (long)MROWS * DIM;

    const dim3 blk(256);
    const int gemm_grid = (MROWS / 128) * (DIM / 128);   // 64*6 = 384

    gemm_bt<float, true><<<gemm_grid, blk, 0, stream>>>(q, Wq, bq, Qp);
    gemm_bt<float, true><<<gemm_grid, blk, 0, stream>>>(k, Wk, bk, Kp);
    gemm_bt<float, true><<<gemm_grid, blk, 0, stream>>>(v, Wv, bv, Vp);

    const int attn_grid = BATCH * NHEAD * (SEQ / 64);    // 1536
    attn_kernel<<<attn_grid, blk, 0, stream>>>(Qp, Kp, Vp, attn_bias, attn_mask, Op);

    gemm_bt<short, false><<<gemm_grid, blk, 0, stream>>>(Op, Wo, bo, out);
}